// Round 1
// baseline (638.311 us; speedup 1.0000x reference)
//
#include <hip/hip_runtime.h>
#include <math.h>

constexpr int DD  = 1024;
constexpr int VECN = 3;
constexpr float EPSF = 1e-5f;

// One wave (64 lanes) per batch row n. 4 waves / 256-thread block.
// No LDS, no barriers: shuffle-butterfly reductions only.
__global__ __launch_bounds__(256) void eqln_kernel(
    const float* __restrict__ x, const float* __restrict__ w,
    float* __restrict__ out, int N)
{
    const int lane = threadIdx.x & 63;
    const int wid  = threadIdx.x >> 6;
    const int n = blockIdx.x * 4 + wid;
    if (n >= N) return;

    const float* xp = x   + (size_t)n * (VECN * DD);
    float*       op = out + (size_t)n * (VECN * DD);

    // ---- load 3 rows x 16 floats per lane (float4 coalesced), keep in regs ----
    float xr[3][16];
    #pragma unroll
    for (int a = 0; a < 3; ++a) {
        const float4* src = reinterpret_cast<const float4*>(xp + a * DD);
        #pragma unroll
        for (int c = 0; c < 4; ++c) {
            float4 t = src[c * 64 + lane];
            xr[a][4*c+0] = t.x; xr[a][4*c+1] = t.y;
            xr[a][4*c+2] = t.z; xr[a][4*c+3] = t.w;
        }
    }

    // ---- fused reduction: 3 sums + 6 raw second moments ----
    float red[9];
    #pragma unroll
    for (int i = 0; i < 9; ++i) red[i] = 0.0f;
    #pragma unroll
    for (int j = 0; j < 16; ++j) {
        float x0 = xr[0][j], x1 = xr[1][j], x2 = xr[2][j];
        red[0] += x0; red[1] += x1; red[2] += x2;
        red[3] = fmaf(x0, x0, red[3]);
        red[4] = fmaf(x0, x1, red[4]);
        red[5] = fmaf(x0, x2, red[5]);
        red[6] = fmaf(x1, x1, red[6]);
        red[7] = fmaf(x1, x2, red[7]);
        red[8] = fmaf(x2, x2, red[8]);
    }
    #pragma unroll
    for (int m = 1; m < 64; m <<= 1) {
        #pragma unroll
        for (int i = 0; i < 9; ++i)
            red[i] += __shfl_xor(red[i], m, 64);
    }

    const float invd = 1.0f / (float)DD;
    const float m0 = red[0]*invd, m1 = red[1]*invd, m2 = red[2]*invd;

    // covar = P/d - m m^T + eps*diag(1,2,3)
    float A[3][3];
    A[0][0] = red[3]*invd - m0*m0 + EPSF*1.0f;
    A[0][1] = A[1][0] = red[4]*invd - m0*m1;
    A[0][2] = A[2][0] = red[5]*invd - m0*m2;
    A[1][1] = red[6]*invd - m1*m1 + EPSF*2.0f;
    A[1][2] = A[2][1] = red[7]*invd - m1*m2;
    A[2][2] = red[8]*invd - m2*m2 + EPSF*3.0f;

    // ---- 3x3 symmetric eigendecomposition: cyclic Jacobi, 5 sweeps ----
    // Redundant per-lane (wave-uniform -> no divergence). Orthogonal V to
    // f32 machine eps, so V f(L) V^T is stable even for clustered eigenvalues.
    float V[3][3] = {{1.f,0.f,0.f},{0.f,1.f,0.f},{0.f,0.f,1.f}};
    #pragma unroll
    for (int sweep = 0; sweep < 5; ++sweep) {
        #pragma unroll
        for (int pi = 0; pi < 3; ++pi) {
            const int p = (pi == 2) ? 1 : 0;
            const int q = (pi == 0) ? 1 : 2;
            float apq = A[p][q];
            if (apq * apq > 1e-32f) {
                float tau = (A[q][q] - A[p][p]) / (2.0f * apq);
                float t = copysignf(1.0f, tau) / (fabsf(tau) + sqrtf(fmaf(tau, tau, 1.0f)));
                float c = 1.0f / sqrtf(fmaf(t, t, 1.0f));
                float s = t * c;
                float app = A[p][p], aqq = A[q][q];
                A[p][p] = fmaf(-t, apq, app);
                A[q][q] = fmaf( t, apq, aqq);
                A[p][q] = A[q][p] = 0.0f;
                const int r3 = 3 - p - q;  // the third index
                float arp = A[r3][p], arq = A[r3][q];
                A[r3][p] = A[p][r3] = c*arp - s*arq;
                A[r3][q] = A[q][r3] = s*arp + c*arq;
                #pragma unroll
                for (int r = 0; r < 3; ++r) {
                    float vrp = V[r][p], vrq = V[r][q];
                    V[r][p] = c*vrp - s*vrq;
                    V[r][q] = s*vrp + c*vrq;
                }
            }
        }
    }

    // ---- rank mask (replicates torch/jnp: s > s.max * 3 * f32_eps) + f(s) ----
    float lam[3] = {A[0][0], A[1][1], A[2][2]};
    const float lmax = fmaxf(lam[0], fmaxf(lam[1], lam[2]));
    const float thr = lmax * 3.0f * 1.1920929e-7f;
    #pragma unroll
    for (int i = 0; i < 3; ++i) {
        float s = (lam[i] > thr) ? lam[i] : 0.0f;
        lam[i] = 1.0f / sqrtf(s + EPSF);
    }

    // ---- M = V diag(f) V^T (symmetric) ----
    float M[3][3];
    #pragma unroll
    for (int a = 0; a < 3; ++a) {
        #pragma unroll
        for (int b = a; b < 3; ++b) {
            float acc = lam[0] * V[a][0] * V[b][0];
            acc = fmaf(lam[1] * V[a][1], V[b][1], acc);
            acc = fmaf(lam[2] * V[a][2], V[b][2], acc);
            M[a][b] = acc; M[b][a] = acc;
        }
    }

    // ---- output: out[a] = (M . (x - m)) * weight, float4 stores ----
    const float4* wsrc = reinterpret_cast<const float4*>(w);
    #pragma unroll
    for (int c = 0; c < 4; ++c) {
        float4 wvv = wsrc[c * 64 + lane];
        const float wf[4] = {wvv.x, wvv.y, wvv.z, wvv.w};
        #pragma unroll
        for (int a = 0; a < 3; ++a) {
            float vals[4];
            #pragma unroll
            for (int j = 0; j < 4; ++j) {
                float xc0 = xr[0][4*c+j] - m0;
                float xc1 = xr[1][4*c+j] - m1;
                float xc2 = xr[2][4*c+j] - m2;
                float t = M[a][0] * xc0;
                t = fmaf(M[a][1], xc1, t);
                t = fmaf(M[a][2], xc2, t);
                vals[j] = t * wf[j];
            }
            float4 ov;
            ov.x = vals[0]; ov.y = vals[1]; ov.z = vals[2]; ov.w = vals[3];
            reinterpret_cast<float4*>(op + a * DD)[c * 64 + lane] = ov;
        }
    }
}

extern "C" void kernel_launch(void* const* d_in, const int* in_sizes, int n_in,
                              void* d_out, int out_size, void* d_ws, size_t ws_size,
                              hipStream_t stream) {
    const float* x = (const float*)d_in[0];
    const float* w = (const float*)d_in[1];
    float* out = (float*)d_out;
    const int N = in_sizes[0] / (VECN * DD);   // 32768
    const int blocks = (N + 3) / 4;            // one wave per n, 4 waves/block
    eqln_kernel<<<blocks, 256, 0, stream>>>(x, w, out, N);
}